// Round 13
// baseline (51.764 us; speedup 1.0000x reference)
//
#include <hip/hip_runtime.h>
#include <math.h>

// Biquad peaking EQ over [B=8, C=2, T=1200000] f32.
// Round 13: CALIBRATION. eq_kernel = round 9 verbatim (best, 29.07us).
// Appended: ycopy_kernel — idempotent y->y grid-stride float4 copy
// (75 MB read + 75 MB write), value laundered via inline asm so the
// identity store is not eliminated. Output-preserving => correctness
// unaffected; its rocprof dispatch row directly measures the achievable
// streaming BW for a ~150 MB stream under this harness/graph state.
//   t_copy <= 26us (>=5.8 TB/s): r9's 4.0 TB/s is kernel-internal -> attack.
//   t_copy >= 33us (<=4.5 TB/s): short-stream ceiling -> r9 IS the roofline.

typedef float f32x4 __attribute__((ext_vector_type(4)));

#define T_LEN 1200000
#define NCH   16
#define L     32
#define NR    64
#define NWARM 4
#define OUT_ROWS (NR - NWARM)           // 60
#define OUT_PER_SEG (OUT_ROWS * L)      // 1920
#define SEGS_PER_CH (T_LEN / OUT_PER_SEG)   // 625 (exact)
#define NSEG (SEGS_PER_CH * NCH)        // 10000
#define WPB 4
#define NBLOCKS 1024                    // 4 blocks/CU exactly
#define NWAVES (NBLOCKS * WPB)          // 4096
#define RSTRIDE 36                      // words per row -> minimal b128 banking
#define WAVE_LDS (NR * RSTRIDE)         // 2304 words = 9216 B per wave

#define SCHED_FENCE __builtin_amdgcn_sched_barrier(0)

struct Params {
    float b0, b1, b2, a1, a2;
    float lnr, theta, inv_sinth;
    float C[3][4];                      // M^32, M^64, M^96 row-major
};

struct Seg { const float* xc; float* yc; int g0; };

__device__ __forceinline__ Seg mkseg(int s, const float* __restrict__ x,
                                     float* __restrict__ y)
{
    int ch = s / SEGS_PER_CH;
    int si = s - ch * SEGS_PER_CH;
    Seg g;
    g.xc = x + (size_t)ch * T_LEN;
    g.yc = y + (size_t)ch * T_LEN;
    g.g0 = si * OUT_PER_SEG - NWARM * L;   // -128 only for si == 0
    return g;
}

__device__ __forceinline__ void load_seg(f32x4 r[8], const Seg& s, int lane)
{
    #pragma unroll
    for (int it = 0; it < 8; ++it) {
        int g = s.g0 + (it << 8) + (lane << 2);   // sample index, multiple of 4
        f32x4 v = {0.f, 0.f, 0.f, 0.f};
        if (g >= 0 && g < T_LEN) v = *(const f32x4*)(s.xc + g);
        r[it] = v;
    }
}

__device__ __forceinline__ void stage_seg(float* __restrict__ xs, const f32x4 r[8],
                                          int lane)
{
    const int row0 = lane >> 3, j = (lane & 7) << 2;
    #pragma unroll
    for (int it = 0; it < 8; ++it) {
        int row = (it << 3) + row0;               // matches load_seg layout
        *(f32x4*)&xs[row * RSTRIDE + j] = r[it];
    }
}

__device__ __forceinline__ void process_seg(float* __restrict__ xs,
                                            const Seg& s, int lane,
                                            const Params& P,
                                            const float c1r[4], const float c2r[4])
{
    const int base = lane * RSTRIDE;

    // prev row's x tail — read before in-place y overwrite
    float x1 = 0.f, x2 = 0.f;
    if (lane > 0) {
        x1 = xs[base - RSTRIDE + 31];
        x2 = xs[base - RSTRIDE + 30];
    }
    SCHED_FENCE;

    // zero-state biquad over own row, y written in place (b128 in/out)
    float v1 = 0.f, v2 = 0.f;
    #pragma unroll
    for (int b = 0; b < 8; ++b) {
        f32x4 xv = *(const f32x4*)&xs[base + (b << 2)];
        f32x4 yv;
        #pragma unroll
        for (int k = 0; k < 4; ++k) {
            float xk = xv[k];
            float f  = fmaf(P.b0, xk, fmaf(P.b1, x1, P.b2 * x2));
            float t2 = fmaf(-P.a2, v2, f);
            float yk = fmaf(-P.a1, v1, t2);
            v2 = v1; v1 = yk;
            x2 = x1; x1 = xk;
            yv[k] = yk;
        }
        *(f32x4*)&xs[base + (b << 2)] = yv;
    }

    // entry state via truncated series (independent shuffles):
    // e = v_{-1} + M32*v_{-2} + M64*v_{-3} + M96*v_{-4}
    float q11 = __shfl_up(v1, 1), q21 = __shfl_up(v2, 1);
    float q12 = __shfl_up(v1, 2), q22 = __shfl_up(v2, 2);
    float q13 = __shfl_up(v1, 3), q23 = __shfl_up(v2, 3);
    float q14 = __shfl_up(v1, 4), q24 = __shfl_up(v2, 4);
    if (lane < 1) { q11 = 0.f; q21 = 0.f; }
    if (lane < 2) { q12 = 0.f; q22 = 0.f; }
    if (lane < 3) { q13 = 0.f; q23 = 0.f; }
    if (lane < 4) { q14 = 0.f; q24 = 0.f; }
    float e1 = q11, e2 = q21;
    e1 = fmaf(P.C[0][0], q12, fmaf(P.C[0][1], q22, e1));
    e2 = fmaf(P.C[0][2], q12, fmaf(P.C[0][3], q22, e2));
    e1 = fmaf(P.C[1][0], q13, fmaf(P.C[1][1], q23, e1));
    e2 = fmaf(P.C[1][2], q13, fmaf(P.C[1][3], q23, e2));
    e1 = fmaf(P.C[2][0], q14, fmaf(P.C[2][1], q24, e1));
    e2 = fmaf(P.C[2][2], q14, fmaf(P.C[2][3], q24, e2));

    // store rows 4..63 with fused correction: coalesced float4
    const int j0 = (lane << 2) & 31;
    #pragma unroll
    for (int it = 0; it < 8; ++it) {
        int vo = (it << 6) + lane;
        int row = NWARM + (it << 3) + (lane >> 3);
        row = row > 63 ? 63 : row;               // clamp for shfl on tail lanes
        float al = __shfl(e1, row);
        float be = __shfl(e2, row);
        if (vo < OUT_PER_SEG / 4) {
            f32x4 yv = *(const f32x4*)&xs[row * RSTRIDE + j0];
            f32x4 o;
            #pragma unroll
            for (int k = 0; k < 4; ++k)
                o[k] = fmaf(al, c1r[k], fmaf(be, c2r[k], yv[k]));
            int q = (vo << 2) + NWARM * L;
            *(f32x4*)(s.yc + s.g0 + q) = o;
        }
    }
}

__global__ __launch_bounds__(256, 4) void eq_kernel(const float* __restrict__ x,
                                                    float* __restrict__ y, Params P)
{
    __shared__ __align__(16) float lds[WPB * WAVE_LDS];   // 36864 B
    const int lane = threadIdx.x & 63;
    const int wid  = threadIdx.x >> 6;
    float* xs = lds + wid * WAVE_LDS;
    const int w = blockIdx.x * WPB + wid;                 // 0..4095

    // per-lane correction tables
    float c1r[4], c2r[4];
    {
        const int t0 = (lane << 2) & 31;
        float ph[5];
        #pragma unroll
        for (int k = 0; k < 5; ++k) {
            int t = t0 - 1 + k;
            ph[k] = (t < 0) ? 0.f
                            : expf(t * P.lnr) * sinf((t + 1) * P.theta) * P.inv_sinth;
        }
        #pragma unroll
        for (int k = 0; k < 4; ++k) {
            c1r[k] = fmaf(-P.a1, ph[k + 1], -P.a2 * ph[k]);  // resp. to y[-1]=1
            c2r[k] = -P.a2 * ph[k + 1];                      // resp. to y[-2]=1
        }
    }

    // static balanced assignment: w, w+4096 always valid; w+8192 iff <10000
    const Seg s0 = mkseg(w,          x, y);
    const Seg s1 = mkseg(w + NWAVES, x, y);
    const bool has2 = (w + 2 * NWAVES) < NSEG;
    const Seg s2 = mkseg(has2 ? (w + 2 * NWAVES) : w, x, y);

    f32x4 ra[8], rb[8];
    load_seg(ra, s0, lane);
    load_seg(rb, s1, lane);

    stage_seg(xs, ra, lane); SCHED_FENCE;        // counted vmcnt: waits ra only
    process_seg(xs, s0, lane, P, c1r, c2r);
    SCHED_FENCE;
    if (has2) load_seg(ra, s2, lane);

    stage_seg(xs, rb, lane); SCHED_FENCE;
    process_seg(xs, s1, lane, P, c1r, c2r);
    SCHED_FENCE;

    if (has2) {
        stage_seg(xs, ra, lane); SCHED_FENCE;
        process_seg(xs, s2, lane, P, c1r, c2r);
    }
}

// calibration: idempotent y->y streaming copy. Value laundered through
// inline asm so the identity store cannot be optimized away. Preserves
// output exactly; measures achievable BW for a 75+75 MB stream.
__global__ __launch_bounds__(256) void ycopy_kernel(f32x4* __restrict__ y, int n4)
{
    int i = blockIdx.x * blockDim.x + threadIdx.x;
    int stride = gridDim.x * blockDim.x;
    for (; i < n4; i += stride) {
        f32x4 v = y[i];
        asm volatile("" : "+v"(v));     // opaque: forces real load + store
        y[i] = v;
    }
}

extern "C" void kernel_launch(void* const* d_in, const int* in_sizes, int n_in,
                              void* d_out, int out_size, void* d_ws, size_t ws_size,
                              hipStream_t stream) {
    const float* x = (const float*)d_in[0];
    float* y = (float*)d_out;

    // torchaudio peaking-EQ coefficients (double, then cast — matches ref)
    double w0    = 2.0 * M_PI * 1000.0 / 44100.0;
    double A     = exp(6.0 / 40.0 * log(10.0));
    double al    = sin(w0) / (2.0 * 0.707);
    double b0 = 1.0 + al * A;
    double b1 = -2.0 * cos(w0);
    double b2 = 1.0 - al * A;
    double a0 = 1.0 + al / A;
    double a1 = -2.0 * cos(w0);
    double a2 = 1.0 - al / A;
    b0 /= a0; b1 /= a0; b2 /= a0; a1 /= a0; a2 /= a0;

    Params P;
    P.b0 = (float)b0; P.b1 = (float)b1; P.b2 = (float)b2;
    P.a1 = (float)a1; P.a2 = (float)a2;

    double r     = sqrt(a2);
    double theta = acos(-a1 / (2.0 * r));
    P.lnr = (float)log(r);
    P.theta = (float)theta;
    P.inv_sinth = (float)(1.0 / sin(theta));

    // M^32 via repeated squaring; then M^64, M^96
    double m00 = -a1, m01 = -a2, m10 = 1.0, m11 = 0.0;
    for (int s = 0; s < 5; ++s) {
        double t00 = m00 * m00 + m01 * m10;
        double t01 = m00 * m01 + m01 * m11;
        double t10 = m10 * m00 + m11 * m10;
        double t11 = m10 * m01 + m11 * m11;
        m00 = t00; m01 = t01; m10 = t10; m11 = t11;
    }
    double p00 = m00, p01 = m01, p10 = m10, p11 = m11;    // M^32
    for (int k = 0; k < 3; ++k) {
        P.C[k][0] = (float)p00; P.C[k][1] = (float)p01;
        P.C[k][2] = (float)p10; P.C[k][3] = (float)p11;
        double t00 = p00 * m00 + p01 * m10;               // * M^32
        double t01 = p00 * m01 + p01 * m11;
        double t10 = p10 * m00 + p11 * m10;
        double t11 = p10 * m01 + p11 * m11;
        p00 = t00; p01 = t01; p10 = t10; p11 = t11;
    }

    eq_kernel<<<NBLOCKS, 256, 0, stream>>>(x, y, P);
    // calibration stream: 4.8M float4 = 75 MB read + 75 MB write, idempotent
    ycopy_kernel<<<4096, 256, 0, stream>>>((f32x4*)d_out, out_size / 4);
}

// Round 14
// 38.480 us; speedup vs baseline: 1.3452x; 1.3452x over previous
//
#include <hip/hip_runtime.h>
#include <math.h>

// Biquad peaking EQ over [B=8, C=2, T=1200000] f32.
// Round 14: 32 waves/CU. Round-13 calibration: in-situ streaming ceiling is
// ~21us for 153.6 MB (~7.3 TB/s, L3-warm); r9 exec = 27.5us for 117 MB
// (4.2 TB/s) -> ~25-30% kernel-internal headroom. The copy wins on wave
// concurrency (32/CU) + zero phase structure. This round buys the same:
//  - NO x staging: lane i loads its own 32-sample row (= one 128B line,
//    8 x f32x4) directly to registers. r10 measured this pattern: FETCH
//    stays ~39MB (each line fully consumed by one lane's 8-load burst).
//  - chain1: zero-state biquad reg->reg, y_zs overwrites x in r[8].
//  - entry state via 4-term truncated series (4 indep shfl_up pairs,
//    validated r8/r9/r10, absmax 0.03125 vs threshold 0.119).
//  - correction WITHOUT tables: homogeneous chain h[n]=-a1*h[n-1]-a2*h[n-2]
//    seeded (h[-1],h[-2])=(e1,e2), added into r[] (3 VALU/sample; exact
//    same result as r9's c1/c2 tables, no trig).
//  - y transpose through a HALF buffer twice: rows 0..31 then 32..63 via
//    the same 32x36-word LDS region (4608B/wave). Same-wave LDS is
//    in-order -> no barriers. Block = 4 waves x 4608B = 18432B ->
//    8 blocks/CU = 32 waves/CU (2x r9). All LDS patterns 8-phase minimal.
//  - __launch_bounds__(256,8) pins VGPR <= 64 (est ~52).
//  - 2500 single-segment blocks; hardware backfill; no atomics (r6 lesson).

typedef float f32x4 __attribute__((ext_vector_type(4)));

#define T_LEN 1200000
#define NCH   16
#define L     32
#define NWARM 4
#define OUT_PER_SEG 1920                // 60 rows x 32
#define SEGS_PER_CH (T_LEN / OUT_PER_SEG)   // 625 (exact)
#define NSEG (SEGS_PER_CH * NCH)        // 10000
#define WPB 4
#define NBLOCKS (NSEG / WPB)            // 2500 (exact)
#define RSTRIDE 36                      // words per 32-sample row
#define HALF_LDS (32 * RSTRIDE)         // 1152 words = 4608 B per wave

struct Params {
    float b0, b1, b2, a1, a2;
    float C[3][4];                      // M^32, M^64, M^96 row-major
};

__global__ __launch_bounds__(256, 8) void eq_kernel(const float* __restrict__ x,
                                                    float* __restrict__ y, Params P)
{
    __shared__ __align__(16) float lds[WPB * HALF_LDS];   // 18432 B
    const int lane = threadIdx.x & 63;
    const int wid  = threadIdx.x >> 6;
    float* ys = lds + wid * HALF_LDS;

    const int s  = blockIdx.x * WPB + wid;        // 0..9999, one segment per wave
    const int ch = s / SEGS_PER_CH;
    const int si = s - ch * SEGS_PER_CH;
    const float* __restrict__ xc = x + (size_t)ch * T_LEN;
    float*       __restrict__ yc = y + (size_t)ch * T_LEN;
    const int g0 = si * OUT_PER_SEG - NWARM * L;  // -128 only for si == 0
    const int gl = g0 + (lane << 5);              // lane's row start (128B line)

    // ---- load own row directly to registers (8 x f32x4) ----
    f32x4 r[8];
    #pragma unroll
    for (int k = 0; k < 8; ++k) {
        int g = gl + (k << 2);
        f32x4 v = {0.f, 0.f, 0.f, 0.f};
        if (g >= 0 && g < T_LEN) v = *(const f32x4*)(xc + g);
        r[k] = v;
    }

    // input tail of previous row from neighbor lane
    float tx1 = __shfl_up(r[7].w, 1);             // x[-1]
    float tx2 = __shfl_up(r[7].z, 1);             // x[-2]
    if (lane == 0) { tx1 = 0.f; tx2 = 0.f; }      // exact for si==0

    // ---- chain 1: zero-state biquad, y_zs overwrites x in r[] ----
    float v1 = 0.f, v2 = 0.f;
    {
        float x1 = tx1, x2 = tx2;
        #pragma unroll
        for (int b = 0; b < 8; ++b) {
            f32x4 xv = r[b];
            f32x4 yv;
            #pragma unroll
            for (int k = 0; k < 4; ++k) {
                float xk = xv[k];
                float f  = fmaf(P.b0, xk, fmaf(P.b1, x1, P.b2 * x2));
                float t2 = fmaf(-P.a2, v2, f);
                float yk = fmaf(-P.a1, v1, t2);
                v2 = v1; v1 = yk;
                x2 = x1; x1 = xk;
                yv[k] = yk;
            }
            r[b] = yv;
        }
    }

    // ---- entry state via truncated series (4 independent shuffles) ----
    float q11 = __shfl_up(v1, 1), q21 = __shfl_up(v2, 1);
    float q12 = __shfl_up(v1, 2), q22 = __shfl_up(v2, 2);
    float q13 = __shfl_up(v1, 3), q23 = __shfl_up(v2, 3);
    float q14 = __shfl_up(v1, 4), q24 = __shfl_up(v2, 4);
    if (lane < 1) { q11 = 0.f; q21 = 0.f; }
    if (lane < 2) { q12 = 0.f; q22 = 0.f; }
    if (lane < 3) { q13 = 0.f; q23 = 0.f; }
    if (lane < 4) { q14 = 0.f; q24 = 0.f; }
    float e1 = q11, e2 = q21;                     // (y[-1], y[-2]) of own row
    e1 = fmaf(P.C[0][0], q12, fmaf(P.C[0][1], q22, e1));
    e2 = fmaf(P.C[0][2], q12, fmaf(P.C[0][3], q22, e2));
    e1 = fmaf(P.C[1][0], q13, fmaf(P.C[1][1], q23, e1));
    e2 = fmaf(P.C[1][2], q13, fmaf(P.C[1][3], q23, e2));
    e1 = fmaf(P.C[2][0], q14, fmaf(P.C[2][1], q24, e1));
    e2 = fmaf(P.C[2][2], q14, fmaf(P.C[2][3], q24, e2));

    // ---- homogeneous correction chain added into r[] ----
    // h[-1]=e1, h[-2]=e2; h[n] = -a1*h[n-1] - a2*h[n-2]; y_true = y_zs + h.
    {
        float h1 = e1, h2 = e2;
        #pragma unroll
        for (int b = 0; b < 8; ++b) {
            #pragma unroll
            for (int k = 0; k < 4; ++k) {
                float h = fmaf(-P.a1, h1, -P.a2 * h2);
                r[b][k] += h;
                h2 = h1; h1 = h;
            }
        }
    }

    // ---- output transpose via half-buffer, rows 0..31 then 32..63 ----
    // Same-wave LDS is in-order; same-array variable-index accesses are
    // may-alias so the compiler preserves program order. sched_barrier(0)
    // between phases keeps codegen honest at zero cost.
    #pragma unroll
    for (int h = 0; h < 2; ++h) {
        if ((lane >> 5) == h) {                   // 32 lanes write their rows
            const int row = lane & 31;
            #pragma unroll
            for (int b = 0; b < 8; ++b)
                *(f32x4*)&ys[row * RSTRIDE + (b << 2)] = r[b];
        }
        __builtin_amdgcn_sched_barrier(0);
        #pragma unroll
        for (int it = 0; it < 4; ++it) {          // coalesced read+store 4KB
            int vo  = (it << 6) + lane;           // 0..255
            int q   = vo << 2;                    // 0..1023
            int row = q >> 5;                     // 0..31
            int j   = q & 31;
            if (h == 1 || q >= NWARM * L) {       // skip warm rows in half 0
                f32x4 yv = *(const f32x4*)&ys[row * RSTRIDE + j];
                *(f32x4*)(yc + g0 + (h << 10) + q) = yv;
            }
        }
        __builtin_amdgcn_sched_barrier(0);
    }
}

extern "C" void kernel_launch(void* const* d_in, const int* in_sizes, int n_in,
                              void* d_out, int out_size, void* d_ws, size_t ws_size,
                              hipStream_t stream) {
    const float* x = (const float*)d_in[0];
    float* y = (float*)d_out;

    // torchaudio peaking-EQ coefficients (double, then cast — matches ref)
    double w0    = 2.0 * M_PI * 1000.0 / 44100.0;
    double A     = exp(6.0 / 40.0 * log(10.0));
    double al    = sin(w0) / (2.0 * 0.707);
    double b0 = 1.0 + al * A;
    double b1 = -2.0 * cos(w0);
    double b2 = 1.0 - al * A;
    double a0 = 1.0 + al / A;
    double a1 = -2.0 * cos(w0);
    double a2 = 1.0 - al / A;
    b0 /= a0; b1 /= a0; b2 /= a0; a1 /= a0; a2 /= a0;

    Params P;
    P.b0 = (float)b0; P.b1 = (float)b1; P.b2 = (float)b2;
    P.a1 = (float)a1; P.a2 = (float)a2;

    // M^32 via repeated squaring; then M^64, M^96 (double precision)
    double m00 = -a1, m01 = -a2, m10 = 1.0, m11 = 0.0;
    for (int s = 0; s < 5; ++s) {
        double t00 = m00 * m00 + m01 * m10;
        double t01 = m00 * m01 + m01 * m11;
        double t10 = m10 * m00 + m11 * m10;
        double t11 = m10 * m01 + m11 * m11;
        m00 = t00; m01 = t01; m10 = t10; m11 = t11;
    }
    double p00 = m00, p01 = m01, p10 = m10, p11 = m11;    // M^32
    for (int k = 0; k < 3; ++k) {
        P.C[k][0] = (float)p00; P.C[k][1] = (float)p01;
        P.C[k][2] = (float)p10; P.C[k][3] = (float)p11;
        double t00 = p00 * m00 + p01 * m10;               // * M^32
        double t01 = p00 * m01 + p01 * m11;
        double t10 = p10 * m00 + p11 * m10;
        double t11 = p10 * m01 + p11 * m11;
        p00 = t00; p01 = t01; p10 = t10; p11 = t11;
    }

    eq_kernel<<<NBLOCKS, 256, 0, stream>>>(x, y, P);
}

// Round 15
// 28.969 us; speedup vs baseline: 1.7869x; 1.3283x over previous
//
#include <hip/hip_runtime.h>
#include <math.h>

// Biquad peaking EQ over [B=8, C=2, T=1200000] f32.
// Round 15: RESTORE round 9 verbatim — best measured (29.07us, absmax 0.031).
// Session summary (14 rounds):
//  - Naive per-thread chunks: 113us (latency-bound, uncoalesced).
//  - LDS-staged coalesced + warm-up truncation: 53us.
//  - Affine-scan parallel IIR (shfl_up, M^(32*2^k)): 35us.
//  - + prefetch ping-pong, stride-36 LDS, balance/residency variants,
//    truncated-series states, fence removal: 29.1-30us (r5-r9 plateau).
//  - Probes: graph-node overhead ~1.6us/kernel (r11); in-situ streaming
//    ceiling ~7.3 TB/s L3-warm for 153MB (r13).
//  - Falsified: single-atomic work pool (170us, XCD ping-pong, r6);
//    zero-LDS per-lane rows (uncoalesced stores, 47us, r12); 32 waves/CU
//    register rows (L2 thrash, FETCH +27MB, 38.5us, r14).
// Six structures converge at 29-31us ~= memory stream (115MB, ~16us) +
// imperfectly-overlapped LDS transpose (~6us) + VALU (~4us). Remaining gap
// to the copy bound requires decoupling the read->chain->transpose->write
// dependency, which 6 pipelining attempts did not achieve from HIP source.

typedef float f32x4 __attribute__((ext_vector_type(4)));

#define T_LEN 1200000
#define NCH   16
#define L     32
#define NR    64
#define NWARM 4
#define OUT_ROWS (NR - NWARM)           // 60
#define OUT_PER_SEG (OUT_ROWS * L)      // 1920
#define SEGS_PER_CH (T_LEN / OUT_PER_SEG)   // 625 (exact)
#define NSEG (SEGS_PER_CH * NCH)        // 10000
#define WPB 4
#define NBLOCKS 1024                    // 4 blocks/CU exactly
#define NWAVES (NBLOCKS * WPB)          // 4096
#define RSTRIDE 36                      // words per row -> minimal b128 banking
#define WAVE_LDS (NR * RSTRIDE)         // 2304 words = 9216 B per wave

#define SCHED_FENCE __builtin_amdgcn_sched_barrier(0)

struct Params {
    float b0, b1, b2, a1, a2;
    float lnr, theta, inv_sinth;
    float C[3][4];                      // M^32, M^64, M^96 row-major
};

struct Seg { const float* xc; float* yc; int g0; };

__device__ __forceinline__ Seg mkseg(int s, const float* __restrict__ x,
                                     float* __restrict__ y)
{
    int ch = s / SEGS_PER_CH;
    int si = s - ch * SEGS_PER_CH;
    Seg g;
    g.xc = x + (size_t)ch * T_LEN;
    g.yc = y + (size_t)ch * T_LEN;
    g.g0 = si * OUT_PER_SEG - NWARM * L;   // -128 only for si == 0
    return g;
}

__device__ __forceinline__ void load_seg(f32x4 r[8], const Seg& s, int lane)
{
    #pragma unroll
    for (int it = 0; it < 8; ++it) {
        int g = s.g0 + (it << 8) + (lane << 2);   // sample index, multiple of 4
        f32x4 v = {0.f, 0.f, 0.f, 0.f};
        if (g >= 0 && g < T_LEN) v = *(const f32x4*)(s.xc + g);
        r[it] = v;
    }
}

__device__ __forceinline__ void stage_seg(float* __restrict__ xs, const f32x4 r[8],
                                          int lane)
{
    const int row0 = lane >> 3, j = (lane & 7) << 2;
    #pragma unroll
    for (int it = 0; it < 8; ++it) {
        int row = (it << 3) + row0;               // matches load_seg layout
        *(f32x4*)&xs[row * RSTRIDE + j] = r[it];
    }
}

__device__ __forceinline__ void process_seg(float* __restrict__ xs,
                                            const Seg& s, int lane,
                                            const Params& P,
                                            const float c1r[4], const float c2r[4])
{
    const int base = lane * RSTRIDE;

    // prev row's x tail — read before in-place y overwrite
    float x1 = 0.f, x2 = 0.f;
    if (lane > 0) {
        x1 = xs[base - RSTRIDE + 31];
        x2 = xs[base - RSTRIDE + 30];
    }
    SCHED_FENCE;

    // zero-state biquad over own row, y written in place (b128 in/out)
    float v1 = 0.f, v2 = 0.f;
    #pragma unroll
    for (int b = 0; b < 8; ++b) {
        f32x4 xv = *(const f32x4*)&xs[base + (b << 2)];
        f32x4 yv;
        #pragma unroll
        for (int k = 0; k < 4; ++k) {
            float xk = xv[k];
            float f  = fmaf(P.b0, xk, fmaf(P.b1, x1, P.b2 * x2));
            float t2 = fmaf(-P.a2, v2, f);
            float yk = fmaf(-P.a1, v1, t2);
            v2 = v1; v1 = yk;
            x2 = x1; x1 = xk;
            yv[k] = yk;
        }
        *(f32x4*)&xs[base + (b << 2)] = yv;
    }

    // entry state via truncated series (independent shuffles):
    // e = v_{-1} + M32*v_{-2} + M64*v_{-3} + M96*v_{-4}
    float q11 = __shfl_up(v1, 1), q21 = __shfl_up(v2, 1);
    float q12 = __shfl_up(v1, 2), q22 = __shfl_up(v2, 2);
    float q13 = __shfl_up(v1, 3), q23 = __shfl_up(v2, 3);
    float q14 = __shfl_up(v1, 4), q24 = __shfl_up(v2, 4);
    if (lane < 1) { q11 = 0.f; q21 = 0.f; }
    if (lane < 2) { q12 = 0.f; q22 = 0.f; }
    if (lane < 3) { q13 = 0.f; q23 = 0.f; }
    if (lane < 4) { q14 = 0.f; q24 = 0.f; }
    float e1 = q11, e2 = q21;
    e1 = fmaf(P.C[0][0], q12, fmaf(P.C[0][1], q22, e1));
    e2 = fmaf(P.C[0][2], q12, fmaf(P.C[0][3], q22, e2));
    e1 = fmaf(P.C[1][0], q13, fmaf(P.C[1][1], q23, e1));
    e2 = fmaf(P.C[1][2], q13, fmaf(P.C[1][3], q23, e2));
    e1 = fmaf(P.C[2][0], q14, fmaf(P.C[2][1], q24, e1));
    e2 = fmaf(P.C[2][2], q14, fmaf(P.C[2][3], q24, e2));

    // store rows 4..63 with fused correction: coalesced float4
    const int j0 = (lane << 2) & 31;
    #pragma unroll
    for (int it = 0; it < 8; ++it) {
        int vo = (it << 6) + lane;
        int row = NWARM + (it << 3) + (lane >> 3);
        row = row > 63 ? 63 : row;               // clamp for shfl on tail lanes
        float al = __shfl(e1, row);
        float be = __shfl(e2, row);
        if (vo < OUT_PER_SEG / 4) {
            f32x4 yv = *(const f32x4*)&xs[row * RSTRIDE + j0];
            f32x4 o;
            #pragma unroll
            for (int k = 0; k < 4; ++k)
                o[k] = fmaf(al, c1r[k], fmaf(be, c2r[k], yv[k]));
            int q = (vo << 2) + NWARM * L;
            *(f32x4*)(s.yc + s.g0 + q) = o;
        }
    }
}

__global__ __launch_bounds__(256, 4) void eq_kernel(const float* __restrict__ x,
                                                    float* __restrict__ y, Params P)
{
    __shared__ __align__(16) float lds[WPB * WAVE_LDS];   // 36864 B
    const int lane = threadIdx.x & 63;
    const int wid  = threadIdx.x >> 6;
    float* xs = lds + wid * WAVE_LDS;
    const int w = blockIdx.x * WPB + wid;                 // 0..4095

    // per-lane correction tables
    float c1r[4], c2r[4];
    {
        const int t0 = (lane << 2) & 31;
        float ph[5];
        #pragma unroll
        for (int k = 0; k < 5; ++k) {
            int t = t0 - 1 + k;
            ph[k] = (t < 0) ? 0.f
                            : expf(t * P.lnr) * sinf((t + 1) * P.theta) * P.inv_sinth;
        }
        #pragma unroll
        for (int k = 0; k < 4; ++k) {
            c1r[k] = fmaf(-P.a1, ph[k + 1], -P.a2 * ph[k]);  // resp. to y[-1]=1
            c2r[k] = -P.a2 * ph[k + 1];                      // resp. to y[-2]=1
        }
    }

    // static balanced assignment: w, w+4096 always valid; w+8192 iff <10000
    const Seg s0 = mkseg(w,          x, y);
    const Seg s1 = mkseg(w + NWAVES, x, y);
    const bool has2 = (w + 2 * NWAVES) < NSEG;
    const Seg s2 = mkseg(has2 ? (w + 2 * NWAVES) : w, x, y);

    f32x4 ra[8], rb[8];
    load_seg(ra, s0, lane);
    load_seg(rb, s1, lane);

    stage_seg(xs, ra, lane); SCHED_FENCE;        // counted vmcnt: waits ra only
    process_seg(xs, s0, lane, P, c1r, c2r);
    SCHED_FENCE;
    if (has2) load_seg(ra, s2, lane);

    stage_seg(xs, rb, lane); SCHED_FENCE;
    process_seg(xs, s1, lane, P, c1r, c2r);
    SCHED_FENCE;

    if (has2) {
        stage_seg(xs, ra, lane); SCHED_FENCE;
        process_seg(xs, s2, lane, P, c1r, c2r);
    }
}

extern "C" void kernel_launch(void* const* d_in, const int* in_sizes, int n_in,
                              void* d_out, int out_size, void* d_ws, size_t ws_size,
                              hipStream_t stream) {
    const float* x = (const float*)d_in[0];
    float* y = (float*)d_out;

    // torchaudio peaking-EQ coefficients (double, then cast — matches ref)
    double w0    = 2.0 * M_PI * 1000.0 / 44100.0;
    double A     = exp(6.0 / 40.0 * log(10.0));
    double al    = sin(w0) / (2.0 * 0.707);
    double b0 = 1.0 + al * A;
    double b1 = -2.0 * cos(w0);
    double b2 = 1.0 - al * A;
    double a0 = 1.0 + al / A;
    double a1 = -2.0 * cos(w0);
    double a2 = 1.0 - al / A;
    b0 /= a0; b1 /= a0; b2 /= a0; a1 /= a0; a2 /= a0;

    Params P;
    P.b0 = (float)b0; P.b1 = (float)b1; P.b2 = (float)b2;
    P.a1 = (float)a1; P.a2 = (float)a2;

    double r     = sqrt(a2);
    double theta = acos(-a1 / (2.0 * r));
    P.lnr = (float)log(r);
    P.theta = (float)theta;
    P.inv_sinth = (float)(1.0 / sin(theta));

    // M^32 via repeated squaring; then M^64, M^96
    double m00 = -a1, m01 = -a2, m10 = 1.0, m11 = 0.0;
    for (int s = 0; s < 5; ++s) {
        double t00 = m00 * m00 + m01 * m10;
        double t01 = m00 * m01 + m01 * m11;
        double t10 = m10 * m00 + m11 * m10;
        double t11 = m10 * m01 + m11 * m11;
        m00 = t00; m01 = t01; m10 = t10; m11 = t11;
    }
    double p00 = m00, p01 = m01, p10 = m10, p11 = m11;    // M^32
    for (int k = 0; k < 3; ++k) {
        P.C[k][0] = (float)p00; P.C[k][1] = (float)p01;
        P.C[k][2] = (float)p10; P.C[k][3] = (float)p11;
        double t00 = p00 * m00 + p01 * m10;               // * M^32
        double t01 = p00 * m01 + p01 * m11;
        double t10 = p10 * m00 + p11 * m10;
        double t11 = p10 * m01 + p11 * m11;
        p00 = t00; p01 = t01; p10 = t10; p11 = t11;
    }

    eq_kernel<<<NBLOCKS, 256, 0, stream>>>(x, y, P);
}